// Round 8
// baseline (667.261 us; speedup 1.0000x reference)
//
#include <hip/hip_runtime.h>

#define B_   2
#define S_   1024
#define H_   1024
#define NH_  8
#define HD_  128
#define E_   8
#define MI_  1024
#define SI_  2048
#define T_   2048
#define CAP_ 2048

typedef unsigned short u16;
typedef __attribute__((ext_vector_type(4))) float f32x4;
typedef __attribute__((ext_vector_type(4))) unsigned short u16x4;
typedef __attribute__((ext_vector_type(8))) unsigned short u16x8;
typedef __attribute__((ext_vector_type(8))) __bf16 bf16x8;

__device__ __forceinline__ u16 f2bf(float f) {
  unsigned int u = __builtin_bit_cast(unsigned int, f);
  u = (u + 0x7fffu + ((u >> 16) & 1u)) >> 16;
  return (u16)u;
}
__device__ __forceinline__ float bf2f(u16 u) {
  return __builtin_bit_cast(float, (unsigned int)u << 16);
}
__device__ __forceinline__ float wave_sum(float v) {
#pragma unroll
  for (int o = 32; o; o >>= 1) v += __shfl_down(v, o, 64);
  return v;
}
// async global->LDS, 16B per lane, dest = wave-uniform base + lane*16
__device__ __forceinline__ void gll16(const u16* g, u16* l) {
  __builtin_amdgcn_global_load_lds((const __attribute__((address_space(1))) void*)g,
                                   (__attribute__((address_space(3))) void*)l, 16, 0, 0);
}

// ---------------- weight cvt for MoE/shared rows (row id >= 4096 in unified space).
__device__ __forceinline__ void cvt_moe_rows(
    int row0, int tid,
    const float* __restrict__ eg_w, const float* __restrict__ eu_w,
    const float* __restrict__ ed_w, const float* __restrict__ sg_w,
    const float* __restrict__ su_w, const float* __restrict__ sd_w,
    u16* __restrict__ egu, u16* __restrict__ edb,
    u16* __restrict__ sgu, u16* __restrict__ sdb) {
  const float* src[8];
  u16* dst[8];
#pragma unroll
  for (int g = 0; g < 8; g++) {
    int row = row0 + g;
    if (row < 20480) {                       // expert g/u 16-row interleave
      int rel = row - 4096;                  // [eg: 8192 rows | eu: 8192 rows]
      int zu = rel >= 8192;
      int r = rel & 8191;
      int e = r >> 10, i = r & 1023;
      int orow = (i >> 4) * 32 + (i & 15) + (zu ? 16 : 0);
      src[g] = (zu ? eu_w : eg_w) + (long)r * 1024;
      dst[g] = egu + ((long)e * 2048 + orow) * 1024;
    } else if (row < 28672) {                // ed plain 8M
      long f = (long)(row - 20480) * 1024;
      src[g] = ed_w + f;
      dst[g] = edb + f;
    } else if (row < 32768) {                // shared g/u interleave
      int rel = row - 28672;                 // [sg: 2048 | su: 2048]
      int zu = rel >= 2048;
      int i = rel & 2047;
      int orow = (i >> 4) * 32 + (i & 15) + (zu ? 16 : 0);
      src[g] = (zu ? su_w : sg_w) + (long)i * 1024;
      dst[g] = sgu + (long)orow * 1024;
    } else {                                 // sd plain 2M
      long f = (long)(row - 32768) * 1024;
      src[g] = sd_w + f;
      dst[g] = sdb + f;
    }
  }
  f32x4 v[8];
#pragma unroll
  for (int g = 0; g < 8; g++)
    v[g] = __builtin_nontemporal_load((const f32x4*)src[g] + tid);
#pragma unroll
  for (int g = 0; g < 8; g++) {
    u16x4 o;
#pragma unroll
    for (int c = 0; c < 4; c++) o[c] = f2bf(v[g][c]);
    ((u16x4*)dst[g])[tid] = o;
  }
}

// ---------------- qkv/o weight cvt (512 blocks) + fused RMSNorm1 (2048 blocks).
__global__ void cvt_all(const float* __restrict__ q_w, const float* __restrict__ k_w,
                        const float* __restrict__ v_w, const float* __restrict__ o_w,
                        u16* __restrict__ qwb,
                        const float* __restrict__ hidden, const float* __restrict__ ln1w,
                        u16* __restrict__ xn) {
  int bid = blockIdx.x, tid = threadIdx.x;
  if (bid >= 512) {  // ---- fused RMSNorm -> bf16 (one token row per block)
    int t = bid - 512;
    f32x4 v = ((const f32x4*)(hidden + (long)t * H_))[tid];
    float ss = v[0]*v[0] + v[1]*v[1] + v[2]*v[2] + v[3]*v[3];
    __shared__ float red[4];
    float s = wave_sum(ss);
    if ((tid & 63) == 0) red[tid >> 6] = s;
    __syncthreads();
    float r = rsqrtf((red[0] + red[1] + red[2] + red[3]) * (1.0f / H_) + 1e-6f);
    f32x4 wv = ((const f32x4*)ln1w)[tid];
    u16x4 o;
#pragma unroll
    for (int c = 0; c < 4; c++) o[c] = f2bf(v[c] * r * wv[c]);
    ((u16x4*)(xn + (long)t * H_))[tid] = o;
    return;
  }
  const float* src[8];
  u16* dst[8];
#pragma unroll
  for (int g = 0; g < 8; g++) {
    int row = bid * 8 + g;                   // qkv+o: 4 x 1M contiguous
    int seg = row >> 10;
    const float* in = (seg == 0) ? q_w : (seg == 1) ? k_w : (seg == 2) ? v_w : o_w;
    src[g] = in + (long)(row & 1023) * 1024;
    dst[g] = qwb + (long)row * 1024;
  }
  f32x4 v[8];
#pragma unroll
  for (int g = 0; g < 8; g++)
    v[g] = __builtin_nontemporal_load((const f32x4*)src[g] + tid);
#pragma unroll
  for (int g = 0; g < 8; g++) {
    u16x4 o;
#pragma unroll
    for (int c = 0; c < 4; c++) o[c] = f2bf(v[g][c]);
    ((u16x4*)dst[g])[tid] = o;
  }
}

// ---------------- fused RMSNorm2 + gate + top2 (no atomics)
__global__ void rmsnorm2_gate(const float* __restrict__ x1, const float* __restrict__ ln2w,
                              const float* __restrict__ gw, u16* __restrict__ xn,
                              int* __restrict__ eidx, float* __restrict__ aw) {
  int t = blockIdx.x, tid = threadIdx.x;
  int lane = tid & 63, wave = tid >> 6;
  f32x4 v = ((const f32x4*)(x1 + (long)t * H_))[tid];
  float ss = v[0]*v[0] + v[1]*v[1] + v[2]*v[2] + v[3]*v[3];
  __shared__ float redS[4];
  __shared__ float redE[4][E_];
  float s = wave_sum(ss);
  if (lane == 0) redS[wave] = s;
  __syncthreads();
  float r = rsqrtf((redS[0] + redS[1] + redS[2] + redS[3]) * (1.0f / H_) + 1e-6f);
  f32x4 wv = ((const f32x4*)ln2w)[tid];
  float xv[4];
  u16x4 o;
#pragma unroll
  for (int c = 0; c < 4; c++) { xv[c] = v[c] * r * wv[c]; o[c] = f2bf(xv[c]); }
  ((u16x4*)(xn + (long)t * H_))[tid] = o;
  float acc[E_];
#pragma unroll
  for (int e = 0; e < E_; e++) {
    f32x4 g = ((const f32x4*)(gw + (long)e * H_))[tid];
    acc[e] = xv[0]*g[0] + xv[1]*g[1] + xv[2]*g[2] + xv[3]*g[3];
  }
#pragma unroll
  for (int e = 0; e < E_; e++) acc[e] = wave_sum(acc[e]);
  if (lane == 0)
#pragma unroll
    for (int e = 0; e < E_; e++) redE[wave][e] = acc[e];
  __syncthreads();
  if (tid == 0) {
    float l[E_];
#pragma unroll
    for (int e = 0; e < E_; e++) l[e] = redE[0][e] + redE[1][e] + redE[2][e] + redE[3][e];
    float mx = l[0];
#pragma unroll
    for (int e = 1; e < E_; e++) mx = fmaxf(mx, l[e]);
    float p[E_], z = 0.f;
#pragma unroll
    for (int e = 0; e < E_; e++) { p[e] = __expf(l[e] - mx); z += p[e]; }
    int e0 = 0;
#pragma unroll
    for (int e = 1; e < E_; e++) if (p[e] > p[e0]) e0 = e;
    int e1 = (e0 == 0) ? 1 : 0;
#pragma unroll
    for (int e = 0; e < E_; e++) if (e != e0 && p[e] > p[e1]) e1 = e;
    float q0 = p[e0] / z, q1 = p[e1] / z;
    float invs = 1.0f / (q0 + q1 + 1e-20f);
    eidx[t * 2] = e0;
    eidx[t * 2 + 1] = e1;
    aw[t * 2] = q0 * invs;
    aw[t * 2 + 1] = q1 * invs;
  }
}

// ---------------- single-workgroup routing scan.
// Emits itok, arow AND two XCD-slotted work lists (slot i -> XCD i%8):
//   wgu[640]  (256-gran gu pair):  val = (kind<<12)|(e<<8)|(mt<<4)|nx
//   wdn[1152] (128-gran down pair): val = (kind<<16)|(e<<12)|(mt<<5)|nx
__global__ __launch_bounds__(256) void route_scan(const int* __restrict__ eidx,
                                                  int* __restrict__ arow,
                                                  int* __restrict__ cursor,
                                                  int* __restrict__ itok,
                                                  int* __restrict__ wgu,
                                                  int* __restrict__ wdn) {
  __shared__ int sc[E_][256];
  int tid = threadIdx.x;
  unsigned c0 = 0, c1 = 0;
  int ebuf[16];
#pragma unroll
  for (int i = 0; i < 16; i++) {
    int e = eidx[tid * 16 + i];
    ebuf[i] = e;
    if (e < 4) c0 += 1u << (8 * e); else c1 += 1u << (8 * (e - 4));
  }
#pragma unroll
  for (int e = 0; e < E_; e++)
    sc[e][tid] = (e < 4) ? (int)((c0 >> (8 * e)) & 0xff) : (int)((c1 >> (8 * (e - 4))) & 0xff);
  __syncthreads();
  for (int st = 1; st < 256; st <<= 1) {
    int v[E_];
#pragma unroll
    for (int e = 0; e < E_; e++) v[e] = (tid >= st) ? sc[e][tid - st] : 0;
    __syncthreads();
#pragma unroll
    for (int e = 0; e < E_; e++) sc[e][tid] += v[e];
    __syncthreads();
  }
  // ---- parallel work-list build (totals in sc[e][255] visible to all)
  for (int i = tid; i < 640; i += 256) wgu[i] = -1;
  for (int i = tid; i < 1152; i += 256) wdn[i] = -1;
  __syncthreads();
  if (tid < 8) cursor[tid] = sc[tid][255];
  // gu MoE items: e x (mt<8 x nx<8), keep if mt < nmt256(e)
  for (int i = tid; i < 512; i += 256) {
    int e = i >> 6, item = i & 63;
    int mt = item >> 3, nx = item & 7;
    int nmt = (min(sc[e][255], CAP_) + 255) >> 8;
    if (mt < nmt) wgu[e + 8 * (mt * 8 + nx)] = (0 << 12) | (e << 8) | (mt << 4) | nx;
  }
  // gu shared items: 8 XCDs x 16
  if (tid < 128) {
    int k = tid >> 4, idx = tid & 15;
    int mi = idx >> 2, ni = idx & 3;
    int nmt = (min(sc[k][255], CAP_) + 255) >> 8;
    wgu[k + 8 * (8 * nmt + idx)] = (1 << 12) | ((4 * (k >> 2) + mi) << 4) | (4 * (k & 3) + ni);
  }
  // dn MoE items: e x (mt<16 x nx<8), keep if mt < nmt128(e)
  for (int i = tid; i < 1024; i += 256) {
    int e = i >> 7, item = i & 127;
    int mt = item >> 3, nx = item & 7;
    int nmt = (min(sc[e][255], CAP_) + 127) >> 7;
    if (mt < nmt) wdn[e + 8 * (mt * 8 + nx)] = (0 << 16) | (e << 12) | (mt << 5) | nx;
  }
  // dn shared items: 8 XCDs x 16
  if (tid < 128) {
    int k = tid >> 4, idx = tid & 15;
    int mi = idx >> 2, ni = idx & 3;
    int nmt = (min(sc[k][255], CAP_) + 127) >> 7;
    wdn[k + 8 * (8 * nmt + idx)] = (1 << 16) | ((4 * (k >> 1) + mi) << 5) | (4 * (k & 1) + ni);
  }
  int base[E_];
#pragma unroll
  for (int e = 0; e < E_; e++) {
    int own = (e < 4) ? (int)((c0 >> (8 * e)) & 0xff) : (int)((c1 >> (8 * (e - 4))) & 0xff);
    base[e] = sc[e][tid] - own;
  }
  __syncthreads();
#pragma unroll
  for (int e = 0; e < E_; e++) sc[e][tid] = base[e];
  __syncthreads();
  unsigned r0 = 0, r1 = 0;
#pragma unroll
  for (int i = 0; i < 16; i++) {
    int e = ebuf[i];
    int run = (e < 4) ? (int)((r0 >> (8 * e)) & 0xff) : (int)((r1 >> (8 * (e - 4))) & 0xff);
    int row = e * CAP_ + sc[e][tid] + run;
    arow[tid * 16 + i] = row;
    itok[row] = (tid * 16 + i) >> 1;
    if (e < 4) r0 += 1u << (8 * e); else r1 += 1u << (8 * (e - 4));
  }
}

// ---------------- fused RoPE (vectorized) + V transpose.
__global__ void rope_vtrans(const u16* __restrict__ qkvb, const float* __restrict__ cs,
                            const float* __restrict__ sn, u16* __restrict__ qb,
                            u16* __restrict__ kb, u16* __restrict__ vt) {
  int bid = blockIdx.x, tid = threadIdx.x;
  if (bid < 1024) {
    int z = bid >> 9;
    const u16* src = qkvb + (long)z * 2097152;
    u16* dstb = z ? kb : qb;
    int rb = (bid & 511) * 32 + (tid >> 3);   // row id 0..16383 = (b,s,h)
    int u = tid & 7;
    int h = rb & 7, bs = rb >> 3, s = bs & 1023, b = bs >> 10;
    const u16* row = src + (long)rb * 128;
    int d0 = u * 8;
    u16x8 v1 = *(const u16x8*)(row + d0);
    u16x8 v2 = *(const u16x8*)(row + d0 + 64);
    const float* c1 = cs + s * 128 + d0;
    const float* s1 = sn + s * 128 + d0;
    u16x8 o1, o2;
#pragma unroll
    for (int c = 0; c < 8; c++) {
      float a = bf2f(v1[c]), q2 = bf2f(v2[c]);
      o1[c] = f2bf(a * c1[c] - q2 * s1[c]);
      o2[c] = f2bf(q2 * c1[c + 64] + a * s1[c + 64]);
    }
    u16* orow = dstb + ((long)((b * NH_ + h) * S_ + s)) * HD_;
    *(u16x8*)(orow + d0) = o1;
    *(u16x8*)(orow + d0 + 64) = o2;
  } else {
    int vb = bid - 1024;              // 512 = 16 bh x (16 s-tiles x 2 d-tiles)
    int bh = vb >> 5;
    int rem = vb & 31;
    int s0 = (rem >> 1) * 64, d0 = (rem & 1) * 64;
    int b = bh >> 3, h = bh & 7;
    __shared__ u16 tile[64][68];
    const u16* vsrc = qkvb + 2 * 2097152;
#pragma unroll
    for (int it = 0; it < 4; it++) {
      int idx = it * 256 + tid;
      int r = idx >> 4, c = (idx & 15) * 4;
      u16x4 vv = *(const u16x4*)(vsrc + (((long)(b * S_ + s0 + r)) * NH_ + h) * HD_ + d0 + c);
      *(u16x4*)&tile[r][c] = vv;
    }
    __syncthreads();
#pragma unroll
    for (int it = 0; it < 4; it++) {
      int idx = it * 256 + tid;
      int dr = idx >> 4, sc = (idx & 15) * 4;
      u16x4 ov;
#pragma unroll
      for (int k = 0; k < 4; k++) ov[k] = tile[sc + k][dr];
      *(u16x4*)(vt + ((long)bh * HD_ + d0 + dr) * S_ + s0 + sc) = ov;
    }
  }
}

// ---------------- split-K flash attention partials (Po bf16)
//                + fused MoE/shared weight cvt (blocks >= 640).
__global__ __launch_bounds__(256) void flash_cvt(
    const u16* __restrict__ qb, const u16* __restrict__ kb,
    const u16* __restrict__ vt, u16* __restrict__ Po,
    float* __restrict__ Pm, float* __restrict__ Pl,
    const float* __restrict__ eg_w, const float* __restrict__ eu_w,
    const float* __restrict__ ed_w, const float* __restrict__ sg_w,
    const float* __restrict__ su_w, const float* __restrict__ sd_w,
    u16* __restrict__ egu, u16* __restrict__ edb,
    u16* __restrict__ sgu, u16* __restrict__ sdb) {
  int bid = blockIdx.x;
  int tid = threadIdx.x;
  if (bid >= 640) {  // ---- weight cvt rows (unified row id = 4096 + ...)
    int row0 = 4096 + (bid - 640) * 8;
    cvt_moe_rows(row0, tid, eg_w, eu_w, ed_w, sg_w, su_w, sd_w, egu, edb, sgu, sdb);
    return;
  }
  int item = bid % 40;
  int bh = bid / 40;
  int qt, ch;
  if (item < 4)       { qt = item;                    ch = 0; }
  else if (item < 12) { qt = 4 + ((item - 4) >> 1);   ch = (item - 4) & 1; }
  else if (item < 24) { qt = 8 + (item - 12) / 3;     ch = (item - 12) % 3; }
  else                { qt = 12 + ((item - 24) >> 2); ch = (item - 24) & 3; }
  int j0 = ch * 4, j1 = min(j0 + 4, qt + 1);

  int wavei = tid >> 6, lane = tid & 63;
  int la = lane & 15, qd = lane >> 4;

  __shared__ __align__(16) u16 Ks[64 * 128];
  __shared__ __align__(16) u16 Vs[128 * 64];
  __shared__ __align__(16) u16 Ps[4][16 * 64];

  bf16x8 qf[4];
  const u16* qrow = qb + ((long)bh * S_ + qt * 64 + wavei * 16 + la) * HD_;
#pragma unroll
  for (int ks = 0; ks < 4; ks++)
    qf[ks] = *(const bf16x8*)(qrow + ks * 32 + qd * 8);

  f32x4 oacc[8];
#pragma unroll
  for (int nf = 0; nf < 8; nf++) oacc[nf] = (f32x4){0.f, 0.f, 0.f, 0.f};
  float m_i[4], l_i[4];
#pragma unroll
  for (int r = 0; r < 4; r++) { m_i[r] = -1e30f; l_i[r] = 0.f; }

  const u16* Kbase = kb + (long)bh * S_ * HD_;
  const u16* Vbase = vt + (long)bh * HD_ * S_;
  const float scale = 0.08838834764831845f;
  u16* pw = (u16*)Ps[wavei];
  int swz = la & 7;

  for (int j = j0; j < j1; j++) {
    __syncthreads();
#pragma unroll
    for (int t = 0; t < 4; t++) {
      int blk = t * 4 + wavei;
      int kr = blk * 4 + (lane >> 4);
      int kc = (lane & 15) ^ (kr & 7);
      gll16(Kbase + ((long)j * 64 + kr) * 128 + kc * 8, Ks + blk * 512);
      int vr = blk * 8 + (lane >> 3);
      int vc = (lane & 7) ^ (vr & 7);
      gll16(Vbase + (long)vr * 1024 + j * 64 + vc * 8, Vs + blk * 512);
    }
    __syncthreads();

    f32x4 sacc[4];
#pragma unroll
    for (int jf = 0; jf < 4; jf++) sacc[jf] = (f32x4){0.f, 0.f, 0.f, 0.f};
#pragma unroll
    for (int ks = 0; ks < 4; ks++)
#pragma unroll
      for (int jf = 0; jf < 4; jf++) {
        bf16x8 kfrag = *(const bf16x8*)(Ks + (jf * 16 + la) * 128 + ((ks * 4 + qd) ^ swz) * 8);
        sacc[jf] = __builtin_amdgcn_mfma_f32_16x16x32_bf16(qf[ks], kfrag, sacc[jf], 0, 0, 0);
      }

    float sv[4][4];
    int qglob = qt * 64 + wavei * 16 + qd * 4;
#pragma unroll
    for (int jf = 0; jf < 4; jf++) {
      int kglob = j * 64 + jf * 16 + la;
#pragma unroll
      for (int r = 0; r < 4; r++)
        sv[jf][r] = (kglob <= qglob + r) ? sacc[jf][r] * scale : -1e30f;
    }
    float mnew[4], alpha[4];
#pragma unroll
    for (int r = 0; r < 4; r++) {
      float mx = fmaxf(fmaxf(sv[0][r], sv[1][r]), fmaxf(sv[2][r], sv[3][r]));
#pragma unroll
      for (int o = 1; o < 16; o <<= 1) mx = fmaxf(mx, __shfl_xor(mx, o, 64));
      mnew[r] = fmaxf(m_i[r], mx);
      alpha[r] = __expf(m_i[r] - mnew[r]);
      m_i[r] = mnew[r];
    }
#pragma unroll
    for (int r = 0; r < 4; r++) {
      float sum = 0.f;
#pragma unroll
      for (int jf = 0; jf < 4; jf++) {
        float p = __expf(sv[jf][r] - mnew[r]);
        sv[jf][r] = p;
        sum += p;
      }
#pragma unroll
      for (int o = 1; o < 16; o <<= 1) sum += __shfl_xor(sum, o, 64);
      l_i[r] = l_i[r] * alpha[r] + sum;
    }
#pragma unroll
    for (int jf = 0; jf < 4; jf++)
#pragma unroll
      for (int r = 0; r < 4; r++) {
        int rp = qd * 4 + r;
        int e = jf * 16 + la;
        pw[rp * 64 + (((e >> 3) ^ (rp & 7)) << 3) + (e & 7)] = f2bf(sv[jf][r]);
      }
#pragma unroll
    for (int nf = 0; nf < 8; nf++)
#pragma unroll
      for (int r = 0; r < 4; r++) oacc[nf][r] *= alpha[r];
#pragma unroll
    for (int ks = 0; ks < 2; ks++) {
      bf16x8 pfrag = *(const bf16x8*)(pw + la * 64 + ((ks * 4 + qd) ^ swz) * 8);
#pragma unroll
      for (int nf = 0; nf < 8; nf++) {
        bf16x8 vfrag = *(const bf16x8*)(Vs + (nf * 16 + la) * 64 + (((ks * 4 + qd) & 7) ^ swz) * 8);
        oacc[nf] = __builtin_amdgcn_mfma_f32_16x16x32_bf16(pfrag, vfrag, oacc[nf], 0, 0, 0);
      }
    }
  }

  int pidx = (bh * 16 + qt) * 4 + ch;
  int rowb = wavei * 16 + qd * 4;
  u16* pob = Po + ((long)pidx * 64 + rowb) * 128;
#pragma unroll
  for (int r = 0; r < 4; r++)
#pragma unroll
    for (int nf = 0; nf < 8; nf++)
      pob[(long)r * 128 + nf * 16 + la] = f2bf(oacc[nf][r]);
  if (la == 0)
#pragma unroll
    for (int r = 0; r < 4; r++) {
      Pm[pidx * 64 + rowb + r] = m_i[r];
      Pl[pidx * 64 + rowb + r] = l_i[r];
    }
}

// ---------------- merge split-K partials -> attn (b,s,h*128+d) bf16
__global__ __launch_bounds__(256) void attn_merge(
    const u16* __restrict__ Po, const float* __restrict__ Pm,
    const float* __restrict__ Pl, u16* __restrict__ attn) {
  int qt = blockIdx.x, bh = blockIdx.y;
  int b = bh >> 3, h = bh & 7;
  int nch = (qt >> 2) + 1;
  int t = threadIdx.x;
  int row = t >> 2, cg = (t & 3) * 32;
  long base = (long)(bh * 16 + qt) * 4;
  float mv[4], wv[4];
  float M = -1e30f;
  for (int c = 0; c < nch; c++) { mv[c] = Pm[(base + c) * 64 + row]; M = fmaxf(M, mv[c]); }
  float L = 0.f;
  for (int c = 0; c < nch; c++) { wv[c] = __expf(mv[c] - M); L += wv[c] * Pl[(base + c) * 64 + row]; }
  float inv = 1.0f / L;
  f32x4 o[8];
#pragma unroll
  for (int k = 0; k < 8; k++) o[k] = (f32x4){0.f, 0.f, 0.f, 0.f};
  for (int c = 0; c < nch; c++) {
    const u16x4* src = (const u16x4*)(Po + ((base + c) * 64 + row) * 128 + cg);
#pragma unroll
    for (int k = 0; k < 8; k++) {
      u16x4 sv = src[k];
#pragma unroll
      for (int e = 0; e < 4; e++) o[k][e] += bf2f(sv[e]) * wv[c];
    }
  }
  u16* dst = attn + ((long)b * S_ + qt * 64 + row) * H_ + h * HD_ + cg;
#pragma unroll
  for (int k = 0; k < 8; k++) {
    u16x4 ov;
#pragma unroll
    for (int c = 0; c < 4; c++) ov[c] = f2bf(o[k][c] * inv);
    ((u16x4*)dst)[k] = ov;
  }
}

// ---------------- final: out = x1 + shared + w0*y[r0] + w1*y[r1]
__global__ void final_combine(const float* __restrict__ x1, const float* __restrict__ ys,
                              const u16* __restrict__ y, const int* __restrict__ arow,
                              const float* __restrict__ aw, float* __restrict__ out) {
  int t = blockIdx.x;
  int i = threadIdx.x * 4;
  int r0 = arow[t * 2], r1 = arow[t * 2 + 1];
  float w0 = aw[t * 2], w1 = aw[t * 2 + 1];
  f32x4 a = *(const f32x4*)(x1 + (long)t * H_ + i);
  f32x4 b = *(const f32x4*)(ys + (long)t * H_ + i);
  u16x4 y0 = *(const u16x4*)(y + (long)r0 * H_ + i);
  u16x4 y1 = *(const u16x4*)(y + (long)r1 * H_ + i);
  f32x4 o;
#pragma unroll
  for (int c = 0; c < 4; c++)
    o[c] = a[c] + b[c] + w0 * bf2f(y0[c]) + w1 * bf2f(y1[c]);
  *(f32x4*)(out + (long)t * H_ + i) = o;
}

// ---------------- 256x256 bf16 MFMA GEMM for the gu pair, XCD-slotted 1D grid.
// SINGLE-buffered 64KB LDS -> 2 blocks/CU co-resident: cross-block wave overlap
// hides the per-tile barrier drain (m114), and CUs holding 2 working blocks run
// them concurrently instead of serially (fixes the ~2x tail from nmt spread).
__global__ __launch_bounds__(512, 4) void gemm256(
    const u16* __restrict__ Ag, const u16* __restrict__ Bg, u16* __restrict__ Cg,
    int K, int lda, int ldb, int ldc, long sBz, long sCz,
    const int* __restrict__ itok, const int* __restrict__ wgu,
    const u16* __restrict__ Bg2, u16* __restrict__ Cg2,
    int ldb2, int ldc2) {
  int s = wgu[blockIdx.x];
  if (s < 0) return;
  int kind = s >> 12;
  int z = (s >> 8) & 7;
  int m0 = ((s >> 4) & 15) << 8;
  int n0 = (s & 15) << 8;
  const u16* A = Ag;
  const u16* B;
  u16* C;
  long cbase;
  bool ind;
  if (kind) { B = Bg2; C = Cg2; ldb = ldb2; ldc = ldc2; cbase = 0; ind = false; }
  else      { B = Bg + (long)z * sBz; C = Cg; cbase = (long)z * sCz; ind = true; }

  __shared__ __align__(16) u16 As[256 * 64];
  __shared__ __align__(16) u16 Bs[256 * 64];
  int tid = threadIdx.x;
  int lane = tid & 63, wave = tid >> 6;
  int wr = wave >> 2, wc = wave & 3;      // 2 x 4 wave grid
  int wm = wr * 128, wn = wc * 64;        // per-wave 128x64 C tile
  int la = lane & 15, qd = lane >> 4;
  int sr = lane >> 3;                     // staging row within 8-row group
  int scs = (lane & 7) ^ (sr & 7);        // swizzled source chunk

  const u16* ap[4];
  const u16* bp[4];
#pragma unroll
  for (int r = 0; r < 4; r++) {
    int rloc = m0 + r * 64 + wave * 8 + sr;
    long arow_g = ind ? (long)itok[(long)z * CAP_ + rloc] : (long)rloc;
    ap[r] = A + arow_g * lda + scs * 8;
    bp[r] = B + (long)(n0 + r * 64 + wave * 8 + sr) * ldb + scs * 8;
  }

  f32x4 acc[8][4];
#pragma unroll
  for (int i = 0; i < 8; i++)
#pragma unroll
    for (int j = 0; j < 4; j++) acc[i][j] = (f32x4){0.f, 0.f, 0.f, 0.f};

  int sw = la & 7;
  int nt = K >> 6;
  for (int t = 0; t < nt; ++t) {
    __syncthreads();   // previous tile's readers done
#pragma unroll
    for (int r = 0; r < 4; r++)
      gll16(ap[r] + t * 64, &As[(r * 64 + wave * 8) * 64]);
#pragma unroll
    for (int r = 0; r < 4; r++)
      gll16(bp[r] + t * 64, &Bs[(r * 64 + wave * 8) * 64]);
    __syncthreads();   // drains vmcnt -> staged data visible
#pragma unroll
    for (int kk = 0; kk < 2; kk++) {
      bf16x8 af[8], bfv[4];
#pragma unroll
      for (int i = 0; i < 8; i++)
        af[i] = *(const bf16x8*)(&As[0] + (wm + i * 16 + la) * 64 + (((kk * 4 + qd) ^ sw) << 3));
#pragma unroll
      for (int j = 0; j < 4; j++)
        bfv[j] = *(const bf16x8*)(&Bs[0] + (wn + j * 16 + la) * 64 + (((kk * 4 + qd) ^ sw) << 3));
#pragma unroll
      for (int i = 0; i < 8; i++)
#pragma unroll
        for (int j = 0; j < 4; j++)
          acc[i][j] = __builtin_amdgcn_mfma_f32_16x16x32_bf16(af[i], bfv[j], acc[i][j], 0, 0, 0);
    }
  }

  // SILU(g)*u epilogue (g/u 16-col interleave within 32-col groups)
#pragma unroll
  for (int i = 0; i < 8; i++) {
#pragma unroll
    for (int jp = 0; jp < 2; jp++) {
      int hcol = ((n0 + wn) >> 1) + (jp << 4) + la;
#pragma unroll
      for (int r = 0; r < 4; r++) {
        int row = m0 + wm + i * 16 + qd * 4 + r;
        float g = acc[i][jp * 2][r], u = acc[i][jp * 2 + 1][r];
        float sg = g / (1.f + __expf(-g));
        C[cbase + (long)row * ldc + hcol] = f2bf(sg * u);
      }
    }
  }
}

// ---------------- bf16 MFMA GEMM. BK=64, XOR-swizzled LDS (16B chunk ^= row&7).
// 2-phase double-buffered pipeline with counted vmcnt (no drain in main loop).
// WL==0: 3D grid. WL==3: XCD-slotted 1D grid for the down pair.
template <int MT, int STORE_BF16, int ADD_RES, int FUSE_SILU, int IND, int WL>
__global__ __launch_bounds__(256) void gemm_bt(
    const u16* __restrict__ Ag, const u16* __restrict__ Bg, void* __restrict__ Cg,
    const float* __restrict__ Res, int K, int lda, int ldb, int ldc,
    long sAz, long sBz, long sCz, const int* __restrict__ mlimit,
    const int* __restrict__ itok, const int* __restrict__ wlist,
    const u16* __restrict__ Ag2, const u16* __restrict__ Bg2, void* __restrict__ Cg2,
    int lda2, int ldb2, int ldc2, int K2) {
  constexpr int MR = MT / 32;
  int z = 0, m0, n0, kind = 0;
  const u16 *A, *B;
  void* C;
  long cbase;
  bool ind = (IND != 0);
  if constexpr (WL == 3) {
    int s = wlist[blockIdx.x];
    if (s < 0) return;
    kind = s >> 16;
    m0 = ((s >> 5) & 127) * MT;
    n0 = (s & 31) * 128;
    if (kind) {
      A = Ag2; B = Bg2; C = Cg2;
      lda = lda2; ldb = ldb2; ldc = ldc2; K = K2;
      ind = false;
      cbase = 0;
    } else {
      z = (s >> 12) & 7;
      A = Ag + (IND ? 0 : z * sAz);
      B = Bg + z * sBz;
      C = Cg;
      cbase = (long)z * sCz;
    }
  } else {
    z = blockIdx.z;
    m0 = blockIdx.y * MT;
    n0 = blockIdx.x * 128;
    if (mlimit && m0 >= mlimit[z]) return;
    A = Ag + (IND ? 0 : z * sAz);
    B = Bg + z * sBz;
    C = Cg;
    cbase = (long)z * sCz;
  }

  __shared__ __align__(16) u16 As[2][MT * 64];
  __shared__ __align__(16) u16 Bs[2][128 * 64];
  int tid = threadIdx.x;
  int lane = tid & 63, wave = tid >> 6;
  int wm = (wave & 1) * (MT / 2), wn = (wave >> 1) * 64;
  int la = lane & 15, qd = lane >> 4;
  int sr = lane >> 3;                 // staging row within wave's 8-row group
  int scs = (lane & 7) ^ (sr & 7);    // swizzled source chunk

  const u16* ap[MT / 32];
  const u16* bp[4];
#pragma unroll
  for (int t = 0; t < MT / 32; t++) {
    int rloc = m0 + t * 32 + wave * 8 + sr;
    long arow_g = (IND && ind) ? (long)itok[(long)z * CAP_ + rloc] : (long)rloc;
    ap[t] = A + arow_g * lda + scs * 8;
  }
#pragma unroll
  for (int t = 0; t < 4; t++)
    bp[t] = B + (long)(n0 + t * 32 + wave * 8 + sr) * ldb + scs * 8;

  f32x4 acc[MR][4];
#pragma unroll
  for (int i = 0; i < MR; i++)
#pragma unroll
    for (int j = 0; j < 4; j++) acc[i][j] = (f32x4){0.f, 0.f, 0.f, 0.f};

  auto stage = [&](int buf, int k0) {
#pragma unroll
    for (int t = 0; t < MT / 32; t++)
      gll16(ap[t] + k0, &As[buf][(t * 32 + wave * 8) * 64]);
#pragma unroll
    for (int t = 0; t < 4; t++)
      gll16(bp[t] + k0, &Bs[buf][(t * 32 + wave * 8) * 64]);
  };

  int sw = la & 7;
  int nt = K >> 6;
  int cur = 0;
  stage(0, 0);
  for (int t = 0; t < nt; ++t) {
    if (t + 1 < nt) {
      stage(cur ^ 1, (t + 1) * 64);
      if constexpr (MT == 128)
        asm volatile("s_waitcnt vmcnt(8)" ::: "memory");
      else
        asm volatile("s_waitcnt vmcnt(6)" ::: "memory");
    } else {
      asm volatile("s_waitcnt vmcnt(0)" ::: "memory");
    }
    __builtin_amdgcn_s_barrier();
#pragma unroll
    for (int kk = 0; kk < 2; kk++) {
      bf16x8 af[MR], bfv[4];
#pragma unroll
      for (int i = 0; i < MR; i++)
        af[i] = *(const bf16x8*)(&As[cur][0] + (wm + i * 16 + la) * 64 + (((kk * 4 + qd) ^ sw) << 3));
#pragma unroll
      for (int j = 0; j < 4; j++)
        bfv[j] = *(const bf16x8*)(&Bs[cur][0] + (wn + j * 16 + la) * 64 + (((kk * 4 + qd) ^ sw) << 3));
#pragma unroll
      for (int i = 0; i < MR; i++)
#pragma unroll
        for (int j = 0; j < 4; j++)
          acc[i][j] = __builtin_amdgcn_mfma_f32_16x16x32_bf16(af[i], bfv[j], acc[i][j], 0, 0, 0);
    }
    __builtin_amdgcn_s_barrier();
    cur ^= 1;
  }

  if (FUSE_SILU) {
#pragma unroll
    for (int i = 0; i < MR; i++) {
#pragma unroll
      for (int jp = 0; jp < 2; jp++) {
        int hcol = ((n0 + wn) >> 1) + (jp << 4) + la;
#pragma unroll
        for (int r = 0; r < 4; r++) {
          int row = m0 + wm + i * 16 + qd * 4 + r;
          float g = acc[i][jp * 2][r], u = acc[i][jp * 2 + 1][r];
          float sg = g / (1.f + __expf(-g));
          ((u16*)C)[cbase + (long)row * ldc + hcol] = f2bf(sg * u);
        }
      }
    }
  } else {
    bool sbf = (WL >= 2) ? (kind == 0) : (STORE_BF16 != 0);
#pragma unroll
    for (int i = 0; i < MR; i++) {
#pragma unroll
      for (int j = 0; j < 4; j++) {
        int col = n0 + wn + j * 16 + la;
#pragma unroll
        for (int r = 0; r < 4; r++) {
          int row = m0 + wm + i * 16 + qd * 4 + r;
          float v = acc[i][j][r];
          long ci = cbase + (long)row * ldc + col;
          if (ADD_RES) v += Res[(long)row * ldc + col];
          if (sbf) ((u16*)C)[ci] = f2bf(v);
          else ((float*)C)[ci] = v;
        }
      }
    }
  }
}

extern "C" void kernel_launch(void* const* d_in, const int* in_sizes, int n_in,
                              void* d_out, int out_size, void* d_ws, size_t ws_size,
                              hipStream_t stream) {
  const float* hidden = (const float*)d_in[0];
  const float* ln1w = (const float*)d_in[1];
  const float* ln2w = (const float*)d_in[2];
  const float* q_w = (const float*)d_in[3];
  const float* k_w = (const float*)d_in[4];
  const float* v_w = (const float*)d_in[5];
  const float* o_w = (const float*)d_in[6];
  const float* cosp = (const float*)d_in[7];
  const float* sinp = (const float*)d_in[8];
  const float* gate_w = (const float*)d_in[9];
  const float* eg_w = (const float*)d_in[10];
  const float* eu_w = (const float*)d_in[11];
  const float* ed_w = (const float*)d_in[12];
  const float* sg_w = (const float*)d_in[13];
  const float* su_w = (const float*)d_in[14];
  const float* sd_w = (const float*)d_in[15];
  float* out = (float*)d_out;

  char* w = (char*)d_ws;
  const size_t MB = 1u << 20;
  u16* qwb = (u16*)(w + 0 * MB);     // q,k,v,o bf16, 8MB
  u16* egu = (u16*)(w + 8 * MB);     // (E, 2*MI, H) interleaved g/u, 32MB
  u16* edb = (u16*)(w + 40 * MB);    // (E, H, MI) 16MB
  u16* sgu = (u16*)(w + 56 * MB);    // (2*SI, H) interleaved, 8MB
  u16* sdb = (u16*)(w + 64 * MB);    // (H, SI) 4MB
  float* x1 = (float*)(w + 68 * MB);
  u16* xn = (u16*)(w + 76 * MB);
  u16* attn = (u16*)(w + 80 * MB);
  int* cursor = (int*)(w + 84 * MB);
  int* arow = (int*)(w + 84 * MB + 1024);
  float* aw = (float*)(w + 84 * MB + 20 * 1024);
  int* eidx = (int*)(w + 84 * MB + 40 * 1024);
  int* itok = (int*)(w + 84 * MB + 60 * 1024);  // 64KB
  int* wgu = (int*)(w + 84 * MB + 132 * 1024);  // 640 ints
  int* wdn = (int*)(w + 84 * MB + 136 * 1024);  // 1152 ints
  // phase-1 arena
  u16* qkvb = (u16*)(w + 85 * MB);   // (3, T, H) bf16, 12MB
  u16* qb = (u16*)(w + 109 * MB);
  u16* kb = (u16*)(w + 113 * MB);
  u16* vt = (u16*)(w + 117 * MB);
  u16* Po = (u16*)(w + 121 * MB);      // 1024 x 64 x 128 bf16 = 16.8MB
  float* Pm = (float*)(w + 155 * MB);  // 256KB
  float* Pl = (float*)(w + 156 * MB);  // 256KB
  // phase-2 arena (aliases phase-1)
  u16* hbuf = (u16*)(w + 121 * MB);  // (E,CAP,MI) 32MB
  u16* y = (u16*)(w + 157 * MB);     // (E,CAP,H) 32MB
  u16* hs = (u16*)(w + 189 * MB);    // (T,SI) 8MB
  float* ys = (float*)(w + 197 * MB);  // (T,H) 8MB

  const long M1 = 1048576, M2 = 2097152;

  // ---- qkv/o weight cvt + fused RMSNorm1
  cvt_all<<<2560, 256, 0, stream>>>(q_w, k_w, v_w, o_w, qwb, hidden, ln1w, xn);

  // ---- attention
  gemm_bt<128, 1, 0, 0, 0, 0><<<dim3(8, 16, 3), 256, 0, stream>>>(
      xn, qwb, qkvb, nullptr, 1024, 1024, 1024, 1024, 0, M1, M2, nullptr, nullptr,
      nullptr, nullptr, nullptr, nullptr, 0, 0, 0, 0);
  rope_vtrans<<<1536, 256, 0, stream>>>(qkvb, cosp, sinp, qb, kb, vt);
  // flash attention + overlapped MoE/shared weight cvt (30720 rows = 3840 blocks)
  flash_cvt<<<640 + 3840, 256, 0, stream>>>(qb, kb, vt, Po, Pm, Pl,
                                            eg_w, eu_w, ed_w, sg_w, su_w, sd_w,
                                            egu, edb, sgu, sdb);
  attn_merge<<<dim3(16, 16), 256, 0, stream>>>(Po, Pm, Pl, attn);
  gemm_bt<64, 0, 1, 0, 0, 0><<<dim3(8, 32, 1), 256, 0, stream>>>(
      attn, qwb + 3 * M1, x1, hidden, 1024, 1024, 1024, 1024, 0, 0, 0, nullptr, nullptr,
      nullptr, nullptr, nullptr, nullptr, 0, 0, 0, 0);

  // ---- MoE + shared MLP (XCD-slotted work lists: slot%8 = XCD, B panels L2-pinned)
  rmsnorm2_gate<<<T_, 256, 0, stream>>>(x1, ln2w, gate_w, xn, eidx, aw);
  hipMemsetAsync(itok, 0, E_ * CAP_ * 4, stream);
  route_scan<<<1, 256, 0, stream>>>(eidx, arow, cursor, itok, wgu, wdn);
  // gu pair at 256^2, single-buffer LDS (2 blocks/CU), 1D slotted grid (640 slots)
  gemm256<<<640, 512, 0, stream>>>(
      xn, egu, hbuf, 1024, 1024, 1024, MI_,
      (long)2 * MI_ * H_, (long)CAP_ * MI_, itok, wgu,
      sgu, hs, 1024, SI_);
  // down pair at 128^2, 1D slotted grid (1152 slots)
  gemm_bt<128, 1, 0, 0, 0, 3><<<1152, 256, 0, stream>>>(
      hbuf, edb, y, nullptr, 1024, 1024, 1024, 1024,
      (long)CAP_ * MI_, (long)H_ * MI_, (long)CAP_ * H_, nullptr, nullptr, wdn,
      hs, sdb, ys, 2048, 2048, 1024, 2048);

  final_combine<<<T_, 256, 0, stream>>>(x1, ys, y, arow, aw, out);
}

// Round 10
// 375.813 us; speedup vs baseline: 1.7755x; 1.7755x over previous
//
#include <hip/hip_runtime.h>

#define B_   2
#define S_   1024
#define H_   1024
#define NH_  8
#define HD_  128
#define E_   8
#define MI_  1024
#define SI_  2048
#define T_   2048
#define CAP_ 2048

typedef unsigned short u16;
typedef __attribute__((ext_vector_type(4))) float f32x4;
typedef __attribute__((ext_vector_type(4))) unsigned short u16x4;
typedef __attribute__((ext_vector_type(8))) unsigned short u16x8;
typedef __attribute__((ext_vector_type(8))) __bf16 bf16x8;

__device__ __forceinline__ u16 f2bf(float f) {
  unsigned int u = __builtin_bit_cast(unsigned int, f);
  u = (u + 0x7fffu + ((u >> 16) & 1u)) >> 16;
  return (u16)u;
}
__device__ __forceinline__ float bf2f(u16 u) {
  return __builtin_bit_cast(float, (unsigned int)u << 16);
}
__device__ __forceinline__ float wave_sum(float v) {
#pragma unroll
  for (int o = 32; o; o >>= 1) v += __shfl_down(v, o, 64);
  return v;
}
// async global->LDS, 16B per lane, dest = wave-uniform base + lane*16
__device__ __forceinline__ void gll16(const u16* g, u16* l) {
  __builtin_amdgcn_global_load_lds((const __attribute__((address_space(1))) void*)g,
                                   (__attribute__((address_space(3))) void*)l, 16, 0, 0);
}

// ---------------- weight cvt for MoE/shared rows (row id >= 4096 in unified space).
__device__ __forceinline__ void cvt_moe_rows(
    int row0, int tid,
    const float* __restrict__ eg_w, const float* __restrict__ eu_w,
    const float* __restrict__ ed_w, const float* __restrict__ sg_w,
    const float* __restrict__ su_w, const float* __restrict__ sd_w,
    u16* __restrict__ egu, u16* __restrict__ edb,
    u16* __restrict__ sgu, u16* __restrict__ sdb) {
  const float* src[8];
  u16* dst[8];
#pragma unroll
  for (int g = 0; g < 8; g++) {
    int row = row0 + g;
    if (row < 20480) {                       // expert g/u 16-row interleave
      int rel = row - 4096;                  // [eg: 8192 rows | eu: 8192 rows]
      int zu = rel >= 8192;
      int r = rel & 8191;
      int e = r >> 10, i = r & 1023;
      int orow = (i >> 4) * 32 + (i & 15) + (zu ? 16 : 0);
      src[g] = (zu ? eu_w : eg_w) + (long)r * 1024;
      dst[g] = egu + ((long)e * 2048 + orow) * 1024;
    } else if (row < 28672) {                // ed plain 8M
      long f = (long)(row - 20480) * 1024;
      src[g] = ed_w + f;
      dst[g] = edb + f;
    } else if (row < 32768) {                // shared g/u interleave
      int rel = row - 28672;                 // [sg: 2048 | su: 2048]
      int zu = rel >= 2048;
      int i = rel & 2047;
      int orow = (i >> 4) * 32 + (i & 15) + (zu ? 16 : 0);
      src[g] = (zu ? su_w : sg_w) + (long)i * 1024;
      dst[g] = sgu + (long)orow * 1024;
    } else {                                 // sd plain 2M
      long f = (long)(row - 32768) * 1024;
      src[g] = sd_w + f;
      dst[g] = sdb + f;
    }
  }
  f32x4 v[8];
#pragma unroll
  for (int g = 0; g < 8; g++)
    v[g] = __builtin_nontemporal_load((const f32x4*)src[g] + tid);
#pragma unroll
  for (int g = 0; g < 8; g++) {
    u16x4 o;
#pragma unroll
    for (int c = 0; c < 4; c++) o[c] = f2bf(v[g][c]);
    ((u16x4*)dst[g])[tid] = o;
  }
}

// ---------------- qkv/o weight cvt (512 blocks) + fused RMSNorm1 (2048 blocks).
__global__ void cvt_all(const float* __restrict__ q_w, const float* __restrict__ k_w,
                        const float* __restrict__ v_w, const float* __restrict__ o_w,
                        u16* __restrict__ qwb,
                        const float* __restrict__ hidden, const float* __restrict__ ln1w,
                        u16* __restrict__ xn) {
  int bid = blockIdx.x, tid = threadIdx.x;
  if (bid >= 512) {  // ---- fused RMSNorm -> bf16 (one token row per block)
    int t = bid - 512;
    f32x4 v = ((const f32x4*)(hidden + (long)t * H_))[tid];
    float ss = v[0]*v[0] + v[1]*v[1] + v[2]*v[2] + v[3]*v[3];
    __shared__ float red[4];
    float s = wave_sum(ss);
    if ((tid & 63) == 0) red[tid >> 6] = s;
    __syncthreads();
    float r = rsqrtf((red[0] + red[1] + red[2] + red[3]) * (1.0f / H_) + 1e-6f);
    f32x4 wv = ((const f32x4*)ln1w)[tid];
    u16x4 o;
#pragma unroll
    for (int c = 0; c < 4; c++) o[c] = f2bf(v[c] * r * wv[c]);
    ((u16x4*)(xn + (long)t * H_))[tid] = o;
    return;
  }
  const float* src[8];
  u16* dst[8];
#pragma unroll
  for (int g = 0; g < 8; g++) {
    int row = bid * 8 + g;                   // qkv+o: 4 x 1M contiguous
    int seg = row >> 10;
    const float* in = (seg == 0) ? q_w : (seg == 1) ? k_w : (seg == 2) ? v_w : o_w;
    src[g] = in + (long)(row & 1023) * 1024;
    dst[g] = qwb + (long)row * 1024;
  }
  f32x4 v[8];
#pragma unroll
  for (int g = 0; g < 8; g++)
    v[g] = __builtin_nontemporal_load((const f32x4*)src[g] + tid);
#pragma unroll
  for (int g = 0; g < 8; g++) {
    u16x4 o;
#pragma unroll
    for (int c = 0; c < 4; c++) o[c] = f2bf(v[g][c]);
    ((u16x4*)dst[g])[tid] = o;
  }
}

// ---------------- fused RMSNorm2 + gate + top2 (no atomics)
__global__ void rmsnorm2_gate(const float* __restrict__ x1, const float* __restrict__ ln2w,
                              const float* __restrict__ gw, u16* __restrict__ xn,
                              int* __restrict__ eidx, float* __restrict__ aw) {
  int t = blockIdx.x, tid = threadIdx.x;
  int lane = tid & 63, wave = tid >> 6;
  f32x4 v = ((const f32x4*)(x1 + (long)t * H_))[tid];
  float ss = v[0]*v[0] + v[1]*v[1] + v[2]*v[2] + v[3]*v[3];
  __shared__ float redS[4];
  __shared__ float redE[4][E_];
  float s = wave_sum(ss);
  if (lane == 0) redS[wave] = s;
  __syncthreads();
  float r = rsqrtf((redS[0] + redS[1] + redS[2] + redS[3]) * (1.0f / H_) + 1e-6f);
  f32x4 wv = ((const f32x4*)ln2w)[tid];
  float xv[4];
  u16x4 o;
#pragma unroll
  for (int c = 0; c < 4; c++) { xv[c] = v[c] * r * wv[c]; o[c] = f2bf(xv[c]); }
  ((u16x4*)(xn + (long)t * H_))[tid] = o;
  float acc[E_];
#pragma unroll
  for (int e = 0; e < E_; e++) {
    f32x4 g = ((const f32x4*)(gw + (long)e * H_))[tid];
    acc[e] = xv[0]*g[0] + xv[1]*g[1] + xv[2]*g[2] + xv[3]*g[3];
  }
#pragma unroll
  for (int e = 0; e < E_; e++) acc[e] = wave_sum(acc[e]);
  if (lane == 0)
#pragma unroll
    for (int e = 0; e < E_; e++) redE[wave][e] = acc[e];
  __syncthreads();
  if (tid == 0) {
    float l[E_];
#pragma unroll
    for (int e = 0; e < E_; e++) l[e] = redE[0][e] + redE[1][e] + redE[2][e] + redE[3][e];
    float mx = l[0];
#pragma unroll
    for (int e = 1; e < E_; e++) mx = fmaxf(mx, l[e]);
    float p[E_], z = 0.f;
#pragma unroll
    for (int e = 0; e < E_; e++) { p[e] = __expf(l[e] - mx); z += p[e]; }
    int e0 = 0;
#pragma unroll
    for (int e = 1; e < E_; e++) if (p[e] > p[e0]) e0 = e;
    int e1 = (e0 == 0) ? 1 : 0;
#pragma unroll
    for (int e = 0; e < E_; e++) if (e != e0 && p[e] > p[e1]) e1 = e;
    float q0 = p[e0] / z, q1 = p[e1] / z;
    float invs = 1.0f / (q0 + q1 + 1e-20f);
    eidx[t * 2] = e0;
    eidx[t * 2 + 1] = e1;
    aw[t * 2] = q0 * invs;
    aw[t * 2 + 1] = q1 * invs;
  }
}

// ---------------- single-workgroup routing scan.
// Zeroes itok internally (no separate memset launch), emits itok, arow AND two
// XCD-slotted work lists (slot i -> XCD i%8):
//   wgu[640]  (256-gran gu pair):  val = (kind<<12)|(e<<8)|(mt<<4)|nx
//   wdn[1152] (128-gran down pair): val = (kind<<16)|(e<<12)|(mt<<5)|nx
__global__ __launch_bounds__(256) void route_scan(const int* __restrict__ eidx,
                                                  int* __restrict__ arow,
                                                  int* __restrict__ cursor,
                                                  int* __restrict__ itok,
                                                  int* __restrict__ wgu,
                                                  int* __restrict__ wdn) {
  __shared__ int sc[E_][256];
  int tid = threadIdx.x;
  // zero itok (rows beyond each expert's count must gather a valid token id)
  for (int i = tid; i < E_ * CAP_; i += 256) itok[i] = 0;
  unsigned c0 = 0, c1 = 0;
  int ebuf[16];
#pragma unroll
  for (int i = 0; i < 16; i++) {
    int e = eidx[tid * 16 + i];
    ebuf[i] = e;
    if (e < 4) c0 += 1u << (8 * e); else c1 += 1u << (8 * (e - 4));
  }
#pragma unroll
  for (int e = 0; e < E_; e++)
    sc[e][tid] = (e < 4) ? (int)((c0 >> (8 * e)) & 0xff) : (int)((c1 >> (8 * (e - 4))) & 0xff);
  __syncthreads();
  for (int st = 1; st < 256; st <<= 1) {
    int v[E_];
#pragma unroll
    for (int e = 0; e < E_; e++) v[e] = (tid >= st) ? sc[e][tid - st] : 0;
    __syncthreads();
#pragma unroll
    for (int e = 0; e < E_; e++) sc[e][tid] += v[e];
    __syncthreads();
  }
  // ---- parallel work-list build (totals in sc[e][255] visible to all)
  for (int i = tid; i < 640; i += 256) wgu[i] = -1;
  for (int i = tid; i < 1152; i += 256) wdn[i] = -1;
  __syncthreads();
  if (tid < 8) cursor[tid] = sc[tid][255];
  // gu MoE items: e x (mt<8 x nx<8), keep if mt < nmt256(e)
  for (int i = tid; i < 512; i += 256) {
    int e = i >> 6, item = i & 63;
    int mt = item >> 3, nx = item & 7;
    int nmt = (min(sc[e][255], CAP_) + 255) >> 8;
    if (mt < nmt) wgu[e + 8 * (mt * 8 + nx)] = (0 << 12) | (e << 8) | (mt << 4) | nx;
  }
  // gu shared items: 8 XCDs x 16
  if (tid < 128) {
    int k = tid >> 4, idx = tid & 15;
    int mi = idx >> 2, ni = idx & 3;
    int nmt = (min(sc[k][255], CAP_) + 255) >> 8;
    wgu[k + 8 * (8 * nmt + idx)] = (1 << 12) | ((4 * (k >> 2) + mi) << 4) | (4 * (k & 3) + ni);
  }
  // dn MoE items: e x (mt<16 x nx<8), keep if mt < nmt128(e)
  for (int i = tid; i < 1024; i += 256) {
    int e = i >> 7, item = i & 127;
    int mt = item >> 3, nx = item & 7;
    int nmt = (min(sc[e][255], CAP_) + 127) >> 7;
    if (mt < nmt) wdn[e + 8 * (mt * 8 + nx)] = (0 << 16) | (e << 12) | (mt << 5) | nx;
  }
  // dn shared items: 8 XCDs x 16
  if (tid < 128) {
    int k = tid >> 4, idx = tid & 15;
    int mi = idx >> 2, ni = idx & 3;
    int nmt = (min(sc[k][255], CAP_) + 127) >> 7;
    wdn[k + 8 * (8 * nmt + idx)] = (1 << 16) | ((4 * (k >> 1) + mi) << 5) | (4 * (k & 1) + ni);
  }
  int base[E_];
#pragma unroll
  for (int e = 0; e < E_; e++) {
    int own = (e < 4) ? (int)((c0 >> (8 * e)) & 0xff) : (int)((c1 >> (8 * (e - 4))) & 0xff);
    base[e] = sc[e][tid] - own;
  }
  __syncthreads();
#pragma unroll
  for (int e = 0; e < E_; e++) sc[e][tid] = base[e];
  __syncthreads();
  unsigned r0 = 0, r1 = 0;
#pragma unroll
  for (int i = 0; i < 16; i++) {
    int e = ebuf[i];
    int run = (e < 4) ? (int)((r0 >> (8 * e)) & 0xff) : (int)((r1 >> (8 * (e - 4))) & 0xff);
    int row = e * CAP_ + sc[e][tid] + run;
    arow[tid * 16 + i] = row;
    itok[row] = (tid * 16 + i) >> 1;
    if (e < 4) r0 += 1u << (8 * e); else r1 += 1u << (8 * (e - 4));
  }
}

// ---------------- fused RoPE (vectorized) + V transpose.
__global__ void rope_vtrans(const u16* __restrict__ qkvb, const float* __restrict__ cs,
                            const float* __restrict__ sn, u16* __restrict__ qb,
                            u16* __restrict__ kb, u16* __restrict__ vt) {
  int bid = blockIdx.x, tid = threadIdx.x;
  if (bid < 1024) {
    int z = bid >> 9;
    const u16* src = qkvb + (long)z * 2097152;
    u16* dstb = z ? kb : qb;
    int rb = (bid & 511) * 32 + (tid >> 3);   // row id 0..16383 = (b,s,h)
    int u = tid & 7;
    int h = rb & 7, bs = rb >> 3, s = bs & 1023, b = bs >> 10;
    const u16* row = src + (long)rb * 128;
    int d0 = u * 8;
    u16x8 v1 = *(const u16x8*)(row + d0);
    u16x8 v2 = *(const u16x8*)(row + d0 + 64);
    const float* c1 = cs + s * 128 + d0;
    const float* s1 = sn + s * 128 + d0;
    u16x8 o1, o2;
#pragma unroll
    for (int c = 0; c < 8; c++) {
      float a = bf2f(v1[c]), q2 = bf2f(v2[c]);
      o1[c] = f2bf(a * c1[c] - q2 * s1[c]);
      o2[c] = f2bf(q2 * c1[c + 64] + a * s1[c + 64]);
    }
    u16* orow = dstb + ((long)((b * NH_ + h) * S_ + s)) * HD_;
    *(u16x8*)(orow + d0) = o1;
    *(u16x8*)(orow + d0 + 64) = o2;
  } else {
    int vb = bid - 1024;              // 512 = 16 bh x (16 s-tiles x 2 d-tiles)
    int bh = vb >> 5;
    int rem = vb & 31;
    int s0 = (rem >> 1) * 64, d0 = (rem & 1) * 64;
    int b = bh >> 3, h = bh & 7;
    __shared__ u16 tile[64][68];
    const u16* vsrc = qkvb + 2 * 2097152;
#pragma unroll
    for (int it = 0; it < 4; it++) {
      int idx = it * 256 + tid;
      int r = idx >> 4, c = (idx & 15) * 4;
      u16x4 vv = *(const u16x4*)(vsrc + (((long)(b * S_ + s0 + r)) * NH_ + h) * HD_ + d0 + c);
      *(u16x4*)&tile[r][c] = vv;
    }
    __syncthreads();
#pragma unroll
    for (int it = 0; it < 4; it++) {
      int idx = it * 256 + tid;
      int dr = idx >> 4, sc = (idx & 15) * 4;
      u16x4 ov;
#pragma unroll
      for (int k = 0; k < 4; k++) ov[k] = tile[sc + k][dr];
      *(u16x4*)(vt + ((long)bh * HD_ + d0 + dr) * S_ + s0 + sc) = ov;
    }
  }
}

// ---------------- split-K flash attention partials (Po bf16)
//                + fused MoE/shared weight cvt (blocks >= 640).
__global__ __launch_bounds__(256) void flash_cvt(
    const u16* __restrict__ qb, const u16* __restrict__ kb,
    const u16* __restrict__ vt, u16* __restrict__ Po,
    float* __restrict__ Pm, float* __restrict__ Pl,
    const float* __restrict__ eg_w, const float* __restrict__ eu_w,
    const float* __restrict__ ed_w, const float* __restrict__ sg_w,
    const float* __restrict__ su_w, const float* __restrict__ sd_w,
    u16* __restrict__ egu, u16* __restrict__ edb,
    u16* __restrict__ sgu, u16* __restrict__ sdb) {
  int bid = blockIdx.x;
  int tid = threadIdx.x;
  if (bid >= 640) {  // ---- weight cvt rows (unified row id = 4096 + ...)
    int row0 = 4096 + (bid - 640) * 8;
    cvt_moe_rows(row0, tid, eg_w, eu_w, ed_w, sg_w, su_w, sd_w, egu, edb, sgu, sdb);
    return;
  }
  int item = bid % 40;
  int bh = bid / 40;
  int qt, ch;
  if (item < 4)       { qt = item;                    ch = 0; }
  else if (item < 12) { qt = 4 + ((item - 4) >> 1);   ch = (item - 4) & 1; }
  else if (item < 24) { qt = 8 + (item - 12) / 3;     ch = (item - 12) % 3; }
  else                { qt = 12 + ((item - 24) >> 2); ch = (item - 24) & 3; }
  int j0 = ch * 4, j1 = min(j0 + 4, qt + 1);

  int wavei = tid >> 6, lane = tid & 63;
  int la = lane & 15, qd = lane >> 4;

  __shared__ __align__(16) u16 Ks[64 * 128];
  __shared__ __align__(16) u16 Vs[128 * 64];
  __shared__ __align__(16) u16 Ps[4][16 * 64];

  bf16x8 qf[4];
  const u16* qrow = qb + ((long)bh * S_ + qt * 64 + wavei * 16 + la) * HD_;
#pragma unroll
  for (int ks = 0; ks < 4; ks++)
    qf[ks] = *(const bf16x8*)(qrow + ks * 32 + qd * 8);

  f32x4 oacc[8];
#pragma unroll
  for (int nf = 0; nf < 8; nf++) oacc[nf] = (f32x4){0.f, 0.f, 0.f, 0.f};
  float m_i[4], l_i[4];
#pragma unroll
  for (int r = 0; r < 4; r++) { m_i[r] = -1e30f; l_i[r] = 0.f; }

  const u16* Kbase = kb + (long)bh * S_ * HD_;
  const u16* Vbase = vt + (long)bh * HD_ * S_;
  const float scale = 0.08838834764831845f;
  u16* pw = (u16*)Ps[wavei];
  int swz = la & 7;

  for (int j = j0; j < j1; j++) {
    __syncthreads();
#pragma unroll
    for (int t = 0; t < 4; t++) {
      int blk = t * 4 + wavei;
      int kr = blk * 4 + (lane >> 4);
      int kc = (lane & 15) ^ (kr & 7);
      gll16(Kbase + ((long)j * 64 + kr) * 128 + kc * 8, Ks + blk * 512);
      int vr = blk * 8 + (lane >> 3);
      int vc = (lane & 7) ^ (vr & 7);
      gll16(Vbase + (long)vr * 1024 + j * 64 + vc * 8, Vs + blk * 512);
    }
    __syncthreads();

    f32x4 sacc[4];
#pragma unroll
    for (int jf = 0; jf < 4; jf++) sacc[jf] = (f32x4){0.f, 0.f, 0.f, 0.f};
#pragma unroll
    for (int ks = 0; ks < 4; ks++)
#pragma unroll
      for (int jf = 0; jf < 4; jf++) {
        bf16x8 kfrag = *(const bf16x8*)(Ks + (jf * 16 + la) * 128 + ((ks * 4 + qd) ^ swz) * 8);
        sacc[jf] = __builtin_amdgcn_mfma_f32_16x16x32_bf16(qf[ks], kfrag, sacc[jf], 0, 0, 0);
      }

    float sv[4][4];
    int qglob = qt * 64 + wavei * 16 + qd * 4;
#pragma unroll
    for (int jf = 0; jf < 4; jf++) {
      int kglob = j * 64 + jf * 16 + la;
#pragma unroll
      for (int r = 0; r < 4; r++)
        sv[jf][r] = (kglob <= qglob + r) ? sacc[jf][r] * scale : -1e30f;
    }
    float mnew[4], alpha[4];
#pragma unroll
    for (int r = 0; r < 4; r++) {
      float mx = fmaxf(fmaxf(sv[0][r], sv[1][r]), fmaxf(sv[2][r], sv[3][r]));
#pragma unroll
      for (int o = 1; o < 16; o <<= 1) mx = fmaxf(mx, __shfl_xor(mx, o, 64));
      mnew[r] = fmaxf(m_i[r], mx);
      alpha[r] = __expf(m_i[r] - mnew[r]);
      m_i[r] = mnew[r];
    }
#pragma unroll
    for (int r = 0; r < 4; r++) {
      float sum = 0.f;
#pragma unroll
      for (int jf = 0; jf < 4; jf++) {
        float p = __expf(sv[jf][r] - mnew[r]);
        sv[jf][r] = p;
        sum += p;
      }
#pragma unroll
      for (int o = 1; o < 16; o <<= 1) sum += __shfl_xor(sum, o, 64);
      l_i[r] = l_i[r] * alpha[r] + sum;
    }
#pragma unroll
    for (int jf = 0; jf < 4; jf++)
#pragma unroll
      for (int r = 0; r < 4; r++) {
        int rp = qd * 4 + r;
        int e = jf * 16 + la;
        pw[rp * 64 + (((e >> 3) ^ (rp & 7)) << 3) + (e & 7)] = f2bf(sv[jf][r]);
      }
#pragma unroll
    for (int nf = 0; nf < 8; nf++)
#pragma unroll
      for (int r = 0; r < 4; r++) oacc[nf][r] *= alpha[r];
#pragma unroll
    for (int ks = 0; ks < 2; ks++) {
      bf16x8 pfrag = *(const bf16x8*)(pw + la * 64 + ((ks * 4 + qd) ^ swz) * 8);
#pragma unroll
      for (int nf = 0; nf < 8; nf++) {
        bf16x8 vfrag = *(const bf16x8*)(Vs + (nf * 16 + la) * 64 + (((ks * 4 + qd) & 7) ^ swz) * 8);
        oacc[nf] = __builtin_amdgcn_mfma_f32_16x16x32_bf16(pfrag, vfrag, oacc[nf], 0, 0, 0);
      }
    }
  }

  int pidx = (bh * 16 + qt) * 4 + ch;
  int rowb = wavei * 16 + qd * 4;
  u16* pob = Po + ((long)pidx * 64 + rowb) * 128;
#pragma unroll
  for (int r = 0; r < 4; r++)
#pragma unroll
    for (int nf = 0; nf < 8; nf++)
      pob[(long)r * 128 + nf * 16 + la] = f2bf(oacc[nf][r]);
  if (la == 0)
#pragma unroll
    for (int r = 0; r < 4; r++) {
      Pm[pidx * 64 + rowb + r] = m_i[r];
      Pl[pidx * 64 + rowb + r] = l_i[r];
    }
}

// ---------------- merge split-K partials -> attn (b,s,h*128+d) bf16
__global__ __launch_bounds__(256) void attn_merge(
    const u16* __restrict__ Po, const float* __restrict__ Pm,
    const float* __restrict__ Pl, u16* __restrict__ attn) {
  int qt = blockIdx.x, bh = blockIdx.y;
  int b = bh >> 3, h = bh & 7;
  int nch = (qt >> 2) + 1;
  int t = threadIdx.x;
  int row = t >> 2, cg = (t & 3) * 32;
  long base = (long)(bh * 16 + qt) * 4;
  float mv[4], wv[4];
  float M = -1e30f;
  for (int c = 0; c < nch; c++) { mv[c] = Pm[(base + c) * 64 + row]; M = fmaxf(M, mv[c]); }
  float L = 0.f;
  for (int c = 0; c < nch; c++) { wv[c] = __expf(mv[c] - M); L += wv[c] * Pl[(base + c) * 64 + row]; }
  float inv = 1.0f / L;
  f32x4 o[8];
#pragma unroll
  for (int k = 0; k < 8; k++) o[k] = (f32x4){0.f, 0.f, 0.f, 0.f};
  for (int c = 0; c < nch; c++) {
    const u16x4* src = (const u16x4*)(Po + ((base + c) * 64 + row) * 128 + cg);
#pragma unroll
    for (int k = 0; k < 8; k++) {
      u16x4 sv = src[k];
#pragma unroll
      for (int e = 0; e < 4; e++) o[k][e] += bf2f(sv[e]) * wv[c];
    }
  }
  u16* dst = attn + ((long)b * S_ + qt * 64 + row) * H_ + h * HD_ + cg;
#pragma unroll
  for (int k = 0; k < 8; k++) {
    u16x4 ov;
#pragma unroll
    for (int c = 0; c < 4; c++) ov[c] = f2bf(o[k][c] * inv);
    ((u16x4*)dst)[k] = ov;
  }
}

// ---------------- final: out = x1 + shared + w0*y[r0] + w1*y[r1]
__global__ void final_combine(const float* __restrict__ x1, const float* __restrict__ ys,
                              const u16* __restrict__ y, const int* __restrict__ arow,
                              const float* __restrict__ aw, float* __restrict__ out) {
  int t = blockIdx.x;
  int i = threadIdx.x * 4;
  int r0 = arow[t * 2], r1 = arow[t * 2 + 1];
  float w0 = aw[t * 2], w1 = aw[t * 2 + 1];
  f32x4 a = *(const f32x4*)(x1 + (long)t * H_ + i);
  f32x4 b = *(const f32x4*)(ys + (long)t * H_ + i);
  u16x4 y0 = *(const u16x4*)(y + (long)r0 * H_ + i);
  u16x4 y1 = *(const u16x4*)(y + (long)r1 * H_ + i);
  f32x4 o;
#pragma unroll
  for (int c = 0; c < 4; c++)
    o[c] = a[c] + b[c] + w0 * bf2f(y0[c]) + w1 * bf2f(y1[c]);
  *(f32x4*)(out + (long)t * H_ + i) = o;
}

// ---------------- 256x256 bf16 MFMA GEMM for the gu pair, XCD-slotted 1D grid.
// slot = blockIdx.x -> XCD slot%8; work item from wgu (see route_scan).
// Double-buffered 128KB LDS, counted vmcnt(8) pipeline (r7-verified config;
// NOTE: 256^2 acc needs 128 VGPR/lane -> 1 block/CU is the only valid occupancy,
// forcing 2-residency via launch_bounds spills the accumulators, 5x regression).
__global__ __launch_bounds__(512) void gemm256(
    const u16* __restrict__ Ag, const u16* __restrict__ Bg, u16* __restrict__ Cg,
    int K, int lda, int ldb, int ldc, long sBz, long sCz,
    const int* __restrict__ itok, const int* __restrict__ wgu,
    const u16* __restrict__ Bg2, u16* __restrict__ Cg2,
    int ldb2, int ldc2) {
  int s = wgu[blockIdx.x];
  if (s < 0) return;
  int kind = s >> 12;
  int z = (s >> 8) & 7;
  int m0 = ((s >> 4) & 15) << 8;
  int n0 = (s & 15) << 8;
  const u16* A = Ag;
  const u16* B;
  u16* C;
  long cbase;
  bool ind;
  if (kind) { B = Bg2; C = Cg2; ldb = ldb2; ldc = ldc2; cbase = 0; ind = false; }
  else      { B = Bg + (long)z * sBz; C = Cg; cbase = (long)z * sCz; ind = true; }

  __shared__ __align__(16) u16 As[2][256 * 64];
  __shared__ __align__(16) u16 Bs[2][256 * 64];
  int tid = threadIdx.x;
  int lane = tid & 63, wave = tid >> 6;
  int wr = wave >> 2, wc = wave & 3;      // 2 x 4 wave grid
  int wm = wr * 128, wn = wc * 64;        // per-wave 128x64 C tile
  int la = lane & 15, qd = lane >> 4;
  int sr = lane >> 3;                     // staging row within 8-row group
  int scs = (lane & 7) ^ (sr & 7);        // swizzled source chunk

  const u16* ap[4];
  const u16* bp[4];
#pragma unroll
  for (int r = 0; r < 4; r++) {
    int rloc = m0 + r * 64 + wave * 8 + sr;
    long arow_g = ind ? (long)itok[(long)z * CAP_ + rloc] : (long)rloc;
    ap[r] = A + arow_g * lda + scs * 8;
    bp[r] = B + (long)(n0 + r * 64 + wave * 8 + sr) * ldb + scs * 8;
  }

  f32x4 acc[8][4];
#pragma unroll
  for (int i = 0; i < 8; i++)
#pragma unroll
    for (int j = 0; j < 4; j++) acc[i][j] = (f32x4){0.f, 0.f, 0.f, 0.f};

  auto stage = [&](int buf, int k0) {
#pragma unroll
    for (int r = 0; r < 4; r++)
      gll16(ap[r] + k0, &As[buf][(r * 64 + wave * 8) * 64]);
#pragma unroll
    for (int r = 0; r < 4; r++)
      gll16(bp[r] + k0, &Bs[buf][(r * 64 + wave * 8) * 64]);
  };

  int sw = la & 7;
  int nt = K >> 6;
  int cur = 0;
  stage(0, 0);
  for (int t = 0; t < nt; ++t) {
    if (t + 1 < nt) {
      stage(cur ^ 1, (t + 1) * 64);
      asm volatile("s_waitcnt vmcnt(8)" ::: "memory");
    } else {
      asm volatile("s_waitcnt vmcnt(0)" ::: "memory");
    }
    __builtin_amdgcn_s_barrier();
#pragma unroll
    for (int kk = 0; kk < 2; kk++) {
      bf16x8 af[8], bfv[4];
#pragma unroll
      for (int i = 0; i < 8; i++)
        af[i] = *(const bf16x8*)(&As[cur][0] + (wm + i * 16 + la) * 64 + (((kk * 4 + qd) ^ sw) << 3));
#pragma unroll
      for (int j = 0; j < 4; j++)
        bfv[j] = *(const bf16x8*)(&Bs[cur][0] + (wn + j * 16 + la) * 64 + (((kk * 4 + qd) ^ sw) << 3));
#pragma unroll
      for (int i = 0; i < 8; i++)
#pragma unroll
        for (int j = 0; j < 4; j++)
          acc[i][j] = __builtin_amdgcn_mfma_f32_16x16x32_bf16(af[i], bfv[j], acc[i][j], 0, 0, 0);
    }
    __builtin_amdgcn_s_barrier();
    cur ^= 1;
  }

  // SILU(g)*u epilogue (g/u 16-col interleave within 32-col groups)
#pragma unroll
  for (int i = 0; i < 8; i++) {
#pragma unroll
    for (int jp = 0; jp < 2; jp++) {
      int hcol = ((n0 + wn) >> 1) + (jp << 4) + la;
#pragma unroll
      for (int r = 0; r < 4; r++) {
        int row = m0 + wm + i * 16 + qd * 4 + r;
        float g = acc[i][jp * 2][r], u = acc[i][jp * 2 + 1][r];
        float sg = g / (1.f + __expf(-g));
        C[cbase + (long)row * ldc + hcol] = f2bf(sg * u);
      }
    }
  }
}

// ---------------- bf16 MFMA GEMM. BK=64, XOR-swizzled LDS (16B chunk ^= row&7).
// 2-phase double-buffered pipeline with counted vmcnt (no drain in main loop).
// WL==0: 3D grid. WL==3: XCD-slotted 1D grid for the down pair.
template <int MT, int STORE_BF16, int ADD_RES, int FUSE_SILU, int IND, int WL>
__global__ __launch_bounds__(256) void gemm_bt(
    const u16* __restrict__ Ag, const u16* __restrict__ Bg, void* __restrict__ Cg,
    const float* __restrict__ Res, int K, int lda, int ldb, int ldc,
    long sAz, long sBz, long sCz, const int* __restrict__ mlimit,
    const int* __restrict__ itok, const int* __restrict__ wlist,
    const u16* __restrict__ Ag2, const u16* __restrict__ Bg2, void* __restrict__ Cg2,
    int lda2, int ldb2, int ldc2, int K2) {
  constexpr int MR = MT / 32;
  int z = 0, m0, n0, kind = 0;
  const u16 *A, *B;
  void* C;
  long cbase;
  bool ind = (IND != 0);
  if constexpr (WL == 3) {
    int s = wlist[blockIdx.x];
    if (s < 0) return;
    kind = s >> 16;
    m0 = ((s >> 5) & 127) * MT;
    n0 = (s & 31) * 128;
    if (kind) {
      A = Ag2; B = Bg2; C = Cg2;
      lda = lda2; ldb = ldb2; ldc = ldc2; K = K2;
      ind = false;
      cbase = 0;
    } else {
      z = (s >> 12) & 7;
      A = Ag + (IND ? 0 : z * sAz);
      B = Bg + z * sBz;
      C = Cg;
      cbase = (long)z * sCz;
    }
  } else {
    z = blockIdx.z;
    m0 = blockIdx.y * MT;
    n0 = blockIdx.x * 128;
    if (mlimit && m0 >= mlimit[z]) return;
    A = Ag + (IND ? 0 : z * sAz);
    B = Bg + z * sBz;
    C = Cg;
    cbase = (long)z * sCz;
  }

  __shared__ __align__(16) u16 As[2][MT * 64];
  __shared__ __align__(16) u16 Bs[2][128 * 64];
  int tid = threadIdx.x;
  int lane = tid & 63, wave = tid >> 6;
  int wm = (wave & 1) * (MT / 2), wn = (wave >> 1) * 64;
  int la = lane & 15, qd = lane >> 4;
  int sr = lane >> 3;                 // staging row within wave's 8-row group
  int scs = (lane & 7) ^ (sr & 7);    // swizzled source chunk

  const u16* ap[MT / 32];
  const u16* bp[4];
#pragma unroll
  for (int t = 0; t < MT / 32; t++) {
    int rloc = m0 + t * 32 + wave * 8 + sr;
    long arow_g = (IND && ind) ? (long)itok[(long)z * CAP_ + rloc] : (long)rloc;
    ap[t] = A + arow_g * lda + scs * 8;
  }
#pragma unroll
  for (int t = 0; t < 4; t++)
    bp[t] = B + (long)(n0 + t * 32 + wave * 8 + sr) * ldb + scs * 8;

  f32x4 acc[MR][4];
#pragma unroll
  for (int i = 0; i < MR; i++)
#pragma unroll
    for (int j = 0; j < 4; j++) acc[i][j] = (f32x4){0.f, 0.f, 0.f, 0.f};

  auto stage = [&](int buf, int k0) {
#pragma unroll
    for (int t = 0; t < MT / 32; t++)
      gll16(ap[t] + k0, &As[buf][(t * 32 + wave * 8) * 64]);
#pragma unroll
    for (int t = 0; t < 4; t++)
      gll16(bp[t] + k0, &Bs[buf][(t * 32 + wave * 8) * 64]);
  };

  int sw = la & 7;
  int nt = K >> 6;
  int cur = 0;
  stage(0, 0);
  for (int t = 0; t < nt; ++t) {
    if (t + 1 < nt) {
      stage(cur ^ 1, (t + 1) * 64);
      if constexpr (MT == 128)
        asm volatile("s_waitcnt vmcnt(8)" ::: "memory");
      else
        asm volatile("s_waitcnt vmcnt(6)" ::: "memory");
    } else {
      asm volatile("s_waitcnt vmcnt(0)" ::: "memory");
    }
    __builtin_amdgcn_s_barrier();
#pragma unroll
    for (int kk = 0; kk < 2; kk++) {
      bf16x8 af[MR], bfv[4];
#pragma unroll
      for (int i = 0; i < MR; i++)
        af[i] = *(const bf16x8*)(&As[cur][0] + (wm + i * 16 + la) * 64 + (((kk * 4 + qd) ^ sw) << 3));
#pragma unroll
      for (int j = 0; j < 4; j++)
        bfv[j] = *(const bf16x8*)(&Bs[cur][0] + (wn + j * 16 + la) * 64 + (((kk * 4 + qd) ^ sw) << 3));
#pragma unroll
      for (int i = 0; i < MR; i++)
#pragma unroll
        for (int j = 0; j < 4; j++)
          acc[i][j] = __builtin_amdgcn_mfma_f32_16x16x32_bf16(af[i], bfv[j], acc[i][j], 0, 0, 0);
    }
    __builtin_amdgcn_s_barrier();
    cur ^= 1;
  }

  if (FUSE_SILU) {
#pragma unroll
    for (int i = 0; i < MR; i++) {
#pragma unroll
      for (int jp = 0; jp < 2; jp++) {
        int hcol = ((n0 + wn) >> 1) + (jp << 4) + la;
#pragma unroll
        for (int r = 0; r < 4; r++) {
          int row = m0 + wm + i * 16 + qd * 4 + r;
          float g = acc[i][jp * 2][r], u = acc[i][jp * 2 + 1][r];
          float sg = g / (1.f + __expf(-g));
          ((u16*)C)[cbase + (long)row * ldc + hcol] = f2bf(sg * u);
        }
      }
    }
  } else {
    bool sbf = (WL >= 2) ? (kind == 0) : (STORE_BF16 != 0);
#pragma unroll
    for (int i = 0; i < MR; i++) {
#pragma unroll
      for (int j = 0; j < 4; j++) {
        int col = n0 + wn + j * 16 + la;
#pragma unroll
        for (int r = 0; r < 4; r++) {
          int row = m0 + wm + i * 16 + qd * 4 + r;
          float v = acc[i][j][r];
          long ci = cbase + (long)row * ldc + col;
          if (ADD_RES) v += Res[(long)row * ldc + col];
          if (sbf) ((u16*)C)[ci] = f2bf(v);
          else ((float*)C)[ci] = v;
        }
      }
    }
  }
}

extern "C" void kernel_launch(void* const* d_in, const int* in_sizes, int n_in,
                              void* d_out, int out_size, void* d_ws, size_t ws_size,
                              hipStream_t stream) {
  const float* hidden = (const float*)d_in[0];
  const float* ln1w = (const float*)d_in[1];
  const float* ln2w = (const float*)d_in[2];
  const float* q_w = (const float*)d_in[3];
  const float* k_w = (const float*)d_in[4];
  const float* v_w = (const float*)d_in[5];
  const float* o_w = (const float*)d_in[6];
  const float* cosp = (const float*)d_in[7];
  const float* sinp = (const float*)d_in[8];
  const float* gate_w = (const float*)d_in[9];
  const float* eg_w = (const float*)d_in[10];
  const float* eu_w = (const float*)d_in[11];
  const float* ed_w = (const float*)d_in[12];
  const float* sg_w = (const float*)d_in[13];
  const float* su_w = (const float*)d_in[14];
  const float* sd_w = (const float*)d_in[15];
  float* out = (float*)d_out;

  char* w = (char*)d_ws;
  const size_t MB = 1u << 20;
  u16* qwb = (u16*)(w + 0 * MB);     // q,k,v,o bf16, 8MB
  u16* egu = (u16*)(w + 8 * MB);     // (E, 2*MI, H) interleaved g/u, 32MB
  u16* edb = (u16*)(w + 40 * MB);    // (E, H, MI) 16MB
  u16* sgu = (u16*)(w + 56 * MB);    // (2*SI, H) interleaved, 8MB
  u16* sdb = (u16*)(w + 64 * MB);    // (H, SI) 4MB
  float* x1 = (float*)(w + 68 * MB);
  u16* xn = (u16*)(w + 76 * MB);
  u16* attn = (u16*)(w + 80 * MB);
  int* cursor = (int*)(w + 84 * MB);
  int* arow = (int*)(w + 84 * MB + 1024);
  float* aw = (float*)(w + 84 * MB + 20 * 1024);
  int* eidx = (int*)(w + 84 * MB + 40 * 1024);
  int* itok = (int*)(w + 84 * MB + 60 * 1024);  // 64KB
  int* wgu = (int*)(w + 84 * MB + 132 * 1024);  // 640 ints
  int* wdn = (int*)(w + 84 * MB + 136 * 1024);  // 1152 ints
  // phase-1 arena
  u16* qkvb = (u16*)(w + 85 * MB);   // (3, T, H) bf16, 12MB
  u16* qb = (u16*)(w + 109 * MB);
  u16* kb = (u16*)(w + 113 * MB);
  u16* vt = (u16*)(w + 117 * MB);
  u16* Po = (u16*)(w + 121 * MB);      // 1024 x 64 x 128 bf16 = 16.8MB
  float* Pm = (float*)(w + 155 * MB);  // 256KB
  float* Pl = (float*)(w + 156 * MB);  // 256KB
  // phase-2 arena (aliases phase-1)
  u16* hbuf = (u16*)(w + 121 * MB);  // (E,CAP,MI) 32MB
  u16* y = (u16*)(w + 157 * MB);     // (E,CAP,H) 32MB
  u16* hs = (u16*)(w + 189 * MB);    // (T,SI) 8MB
  float* ys = (float*)(w + 197 * MB);  // (T,H) 8MB

  const long M1 = 1048576, M2 = 2097152;

  // ---- qkv/o weight cvt + fused RMSNorm1
  cvt_all<<<2560, 256, 0, stream>>>(q_w, k_w, v_w, o_w, qwb, hidden, ln1w, xn);

  // ---- attention
  gemm_bt<128, 1, 0, 0, 0, 0><<<dim3(8, 16, 3), 256, 0, stream>>>(
      xn, qwb, qkvb, nullptr, 1024, 1024, 1024, 1024, 0, M1, M2, nullptr, nullptr,
      nullptr, nullptr, nullptr, nullptr, 0, 0, 0, 0);
  rope_vtrans<<<1536, 256, 0, stream>>>(qkvb, cosp, sinp, qb, kb, vt);
  // flash attention + overlapped MoE/shared weight cvt (30720 rows = 3840 blocks)
  flash_cvt<<<640 + 3840, 256, 0, stream>>>(qb, kb, vt, Po, Pm, Pl,
                                            eg_w, eu_w, ed_w, sg_w, su_w, sd_w,
                                            egu, edb, sgu, sdb);
  attn_merge<<<dim3(16, 16), 256, 0, stream>>>(Po, Pm, Pl, attn);
  gemm_bt<64, 0, 1, 0, 0, 0><<<dim3(8, 32, 1), 256, 0, stream>>>(
      attn, qwb + 3 * M1, x1, hidden, 1024, 1024, 1024, 1024, 0, 0, 0, nullptr, nullptr,
      nullptr, nullptr, nullptr, nullptr, 0, 0, 0, 0);

  // ---- MoE + shared MLP (XCD-slotted work lists: slot%8 = XCD, B panels L2-pinned)
  rmsnorm2_gate<<<T_, 256, 0, stream>>>(x1, ln2w, gate_w, xn, eidx, aw);
  route_scan<<<1, 256, 0, stream>>>(eidx, arow, cursor, itok, wgu, wdn);
  // gu pair at 256^2, dbuf LDS (r7 config), 1D slotted grid (640 slots)
  gemm256<<<640, 512, 0, stream>>>(
      xn, egu, hbuf, 1024, 1024, 1024, MI_,
      (long)2 * MI_ * H_, (long)CAP_ * MI_, itok, wgu,
      sgu, hs, 1024, SI_);
  // down pair at 128^2, 1D slotted grid (1152 slots)
  gemm_bt<128, 1, 0, 0, 0, 3><<<1152, 256, 0, stream>>>(
      hbuf, edb, y, nullptr, 1024, 1024, 1024, 1024,
      (long)CAP_ * MI_, (long)H_ * MI_, (long)CAP_ * H_, nullptr, nullptr, wdn,
      hs, sdb, ys, 2048, 2048, 1024, 2048);

  final_combine<<<T_, 256, 0, stream>>>(x1, ys, y, arow, aw, out);
}